// Round 1
// baseline (257.676 us; speedup 1.0000x reference)
//
#include <hip/hip_runtime.h>
#include <hip/hip_bf16.h>

typedef __bf16 bf16x8 __attribute__((ext_vector_type(8)));
typedef __bf16 bf16x4 __attribute__((ext_vector_type(4)));
typedef float f32x4 __attribute__((ext_vector_type(4)));
typedef unsigned int u32;
typedef __attribute__((address_space(3))) u32 lds_u32_t;
typedef __attribute__((address_space(1))) u32 glb_u32_t;

// Sizes (fixed by the problem)
#define MROWS 8192      // B*S
#define NEXP 4352       // 2*QK + 2*EXPAND
#define DDIM 1024
#define EDIM 2048

__device__ __forceinline__ void async16(const void* g, void* l) {
  __builtin_amdgcn_global_load_lds((const glb_u32_t*)g, (lds_u32_t*)l, 16, 0, 0);
}

// ---------------- LayerNorm + bf16 cast ----------------
__global__ __launch_bounds__(256) void ln_kernel(const float* __restrict__ x,
                                                 const float* __restrict__ wgt,
                                                 __bf16* __restrict__ xn) {
  const int row = blockIdx.x;
  const int t = threadIdx.x;
  const float4 v = ((const float4*)(x + (size_t)row * DDIM))[t];
  float s = v.x + v.y + v.z + v.w;
  float ss = v.x * v.x + v.y * v.y + v.z * v.z + v.w * v.w;
  #pragma unroll
  for (int o = 32; o > 0; o >>= 1) {
    s += __shfl_down(s, o);
    ss += __shfl_down(ss, o);
  }
  __shared__ float red[8];
  const int lane = t & 63, wv = t >> 6;
  if (lane == 0) { red[wv] = s; red[4 + wv] = ss; }
  __syncthreads();
  s = red[0] + red[1] + red[2] + red[3];
  ss = red[4] + red[5] + red[6] + red[7];
  const float mu = s * (1.0f / 1024.0f);
  const float rstd = rsqrtf(ss * (1.0f / 1024.0f) - mu * mu + 1e-5f);
  const float4 w4 = ((const float4*)wgt)[t];
  bf16x4 o;
  o[0] = (__bf16)((v.x - mu) * rstd * w4.x);
  o[1] = (__bf16)((v.y - mu) * rstd * w4.y);
  o[2] = (__bf16)((v.z - mu) * rstd * w4.z);
  o[3] = (__bf16)((v.w - mu) * rstd * w4.w);
  ((bf16x4*)(xn + (size_t)row * DDIM))[t] = o;
}

// ---------------- fp32 -> bf16 weight cast ----------------
__global__ __launch_bounds__(256) void cast_kernel(const float* __restrict__ src,
                                                   __bf16* __restrict__ dst, int n4) {
  const int i = blockIdx.x * 256 + threadIdx.x;
  if (i < n4) {
    const float4 v = ((const float4*)src)[i];
    bf16x4 o;
    o[0] = (__bf16)v.x; o[1] = (__bf16)v.y; o[2] = (__bf16)v.z; o[3] = (__bf16)v.w;
    ((bf16x4*)dst)[i] = o;
  }
}

// ---------------- 128x128 bf16 MFMA GEMM, C = A * Bt^T (both row-major MxK / NxK) ----
// EPI=0: store bf16 C.  EPI=1: store fp32 C = resid + acc.
template <int EPI>
__global__ __launch_bounds__(256) void gemm_bt(const __bf16* __restrict__ A,
                                               const __bf16* __restrict__ Bt,
                                               void* __restrict__ Cout,
                                               const float* __restrict__ resid,
                                               int Ndim, int Kdim) {
  __shared__ __bf16 As[128 * 32];
  __shared__ __bf16 Bs[128 * 32];
  const int t = threadIdx.x;
  const int lane = t & 63;
  const int w = t >> 6;
  const int wm = w >> 1, wn = w & 1;
  const int m0 = blockIdx.x * 128;
  const int n0 = blockIdx.y * 128;

  f32x4 acc[4][4] = {};

  // staging geometry: 8 chunks of 1KB per 8KB tile; wave w owns chunks {2w, 2w+1}
  const int cA = w * 2;
  const int sr = cA * 16 + (lane >> 2);     // tile row for chunk cA
  const int sc = (lane & 3) * 8;            // k-col (8 bf16 = 16B)
  const __bf16* gA0 = A + (size_t)(m0 + sr) * Kdim + sc;
  const __bf16* gA1 = A + (size_t)(m0 + sr + 16) * Kdim + sc;
  const __bf16* gB0 = Bt + (size_t)(n0 + sr) * Kdim + sc;
  const __bf16* gB1 = Bt + (size_t)(n0 + sr + 16) * Kdim + sc;
  __bf16* lA0 = As + cA * 512;
  __bf16* lA1 = As + (cA + 1) * 512;
  __bf16* lB0 = Bs + cA * 512;
  __bf16* lB1 = Bs + (cA + 1) * 512;

  const int lr = lane & 15;
  const int lk = (lane >> 4) * 8;
  const int nk = Kdim >> 5;

  for (int kt = 0; kt < nk; ++kt) {
    __syncthreads();
    const int ko = kt * 32;
    async16(gA0 + ko, lA0);
    async16(gA1 + ko, lA1);
    async16(gB0 + ko, lB0);
    async16(gB1 + ko, lB1);
    __syncthreads();
    bf16x8 a[4], b[4];
    #pragma unroll
    for (int i = 0; i < 4; ++i)
      a[i] = *(const bf16x8*)&As[(wm * 64 + i * 16 + lr) * 32 + lk];
    #pragma unroll
    for (int i = 0; i < 4; ++i)
      b[i] = *(const bf16x8*)&Bs[(wn * 64 + i * 16 + lr) * 32 + lk];
    #pragma unroll
    for (int i = 0; i < 4; ++i)
      #pragma unroll
      for (int j = 0; j < 4; ++j)
        acc[i][j] = __builtin_amdgcn_mfma_f32_16x16x32_bf16(a[i], b[j], acc[i][j], 0, 0, 0);
  }

  // epilogue: C/D layout row=(lane>>4)*4+reg, col=lane&15
  #pragma unroll
  for (int i = 0; i < 4; ++i) {
    const int rbase = m0 + wm * 64 + i * 16 + ((lane >> 4) << 2);
    #pragma unroll
    for (int j = 0; j < 4; ++j) {
      const int col = n0 + wn * 64 + j * 16 + (lane & 15);
      #pragma unroll
      for (int r = 0; r < 4; ++r) {
        const size_t off = (size_t)(rbase + r) * Ndim + col;
        if constexpr (EPI == 0) {
          ((__bf16*)Cout)[off] = (__bf16)acc[i][j][r];
        } else {
          ((float*)Cout)[off] = resid[off] + acc[i][j][r];
        }
      }
    }
  }
}

// ---------------- GEGLU: gl / v from h ----------------
__global__ __launch_bounds__(256) void geglu_kernel(const __bf16* __restrict__ h,
                                                    __bf16* __restrict__ fused,
                                                    __bf16* __restrict__ vbuf) {
  const int idx = blockIdx.x * 256 + threadIdx.x;   // 0 .. 8192*256-1
  const int row = idx >> 8;                         // 256 chunks of 8 per row
  const int col = (idx & 255) * 8;
  const bf16x8 lin = *(const bf16x8*)&h[(size_t)row * NEXP + 256 + col];
  const bf16x8 pre = *(const bf16x8*)&h[(size_t)row * NEXP + 2304 + col];
  bf16x8 o;
  #pragma unroll
  for (int j = 0; j < 8; ++j) {
    const float p = (float)pre[j];
    const float g = 0.5f * p * (1.0f + erff(p * 0.70710678118f));
    o[j] = (__bf16)((float)lin[j] * g);
  }
  if (col < 1024)
    *(bf16x8*)&fused[(size_t)row * EDIM + col] = o;
  else
    *(bf16x8*)&vbuf[(size_t)row * 1024 + (col - 1024)] = o;
}

// ---------------- sliding-window attention (W=32), 1 wave per (b,head,s) ----------
__global__ __launch_bounds__(256) void attn_kernel(const __bf16* __restrict__ h,
                                                   const __bf16* __restrict__ vbuf,
                                                   __bf16* __restrict__ fused,
                                                   const float* __restrict__ pbm) {
  const int gw = blockIdx.x * 4 + (threadIdx.x >> 6);   // 0..32767
  const int lane = threadIdx.x & 63;
  const int s = gw & 1023;
  const int head = (gw >> 10) & 3;
  const int b = gw >> 12;

  const float p = pbm[0];
  const float sp = (p > 20.0f) ? p : log1pf(expf(p));

  const size_t rowq = (size_t)(b * 1024 + s);
  // q (32 dims), broadcast loads
  float q[32];
  const bf16x8* qp = (const bf16x8*)&h[rowq * NEXP + head * 32];
  #pragma unroll
  for (int c = 0; c < 4; ++c) {
    const bf16x8 tq = qp[c];
    #pragma unroll
    for (int j = 0; j < 8; ++j) q[c * 8 + j] = (float)tq[j];
  }

  // scores: key index sk = s-31+jj handled by lane jj (duplicated in upper half)
  const int jj = lane & 31;
  const int sk = s - 31 + jj;
  const int skc = (sk < 0) ? 0 : sk;
  float dot = 0.0f;
  const bf16x8* kp = (const bf16x8*)&h[(size_t)(b * 1024 + skc) * NEXP + 128 + head * 32];
  #pragma unroll
  for (int c = 0; c < 4; ++c) {
    const bf16x8 tk = kp[c];
    #pragma unroll
    for (int j = 0; j < 8; ++j) dot += q[c * 8 + j] * (float)tk[j];
  }
  float score = (sk >= 0) ? (dot * 0.1767766953f + sp * (float)(sk - s)) : -1e30f;

  float mx = score;
  #pragma unroll
  for (int o = 16; o > 0; o >>= 1) mx = fmaxf(mx, __shfl_xor(mx, o));
  const float wgt = expf(score - mx);
  float sum = wgt;
  #pragma unroll
  for (int o = 16; o > 0; o >>= 1) sum += __shfl_xor(sum, o);

  // PV: each lane owns 4 of the 256 v-dims
  float a0 = 0.f, a1 = 0.f, a2 = 0.f, a3 = 0.f;
  const __bf16* vb = vbuf + head * 256 + lane * 4;
  for (int j2 = 0; j2 < 32; ++j2) {
    const int sv = s - 31 + j2;
    if (sv < 0) continue;                 // wave-uniform branch
    const float wj = __shfl(wgt, j2);
    const bf16x4 vv = *(const bf16x4*)&vb[(size_t)(b * 1024 + sv) * 1024];
    a0 += wj * (float)vv[0];
    a1 += wj * (float)vv[1];
    a2 += wj * (float)vv[2];
    a3 += wj * (float)vv[3];
  }
  const float inv = 1.0f / sum;
  bf16x4 o;
  o[0] = (__bf16)(a0 * inv);
  o[1] = (__bf16)(a1 * inv);
  o[2] = (__bf16)(a2 * inv);
  o[3] = (__bf16)(a3 * inv);
  *(bf16x4*)&fused[rowq * EDIM + 1024 + head * 256 + lane * 4] = o;
}

// ---------------- host launch ----------------
extern "C" void kernel_launch(void* const* d_in, const int* in_sizes, int n_in,
                              void* d_out, int out_size, void* d_ws, size_t ws_size,
                              hipStream_t stream) {
  const float* x = (const float*)d_in[0];
  // d_in[1] = attn_mask (tril causal) — structure hard-coded
  const float* norm_w = (const float*)d_in[2];
  const float* expand_w = (const float*)d_in[3];
  const float* project_w = (const float*)d_in[4];
  const float* pbm = (const float*)d_in[5];
  float* out = (float*)d_out;

  char* ws = (char*)d_ws;
  __bf16* xn    = (__bf16*)(ws);                 // 8192*1024*2  = 16,777,216
  __bf16* wexp  = (__bf16*)(ws + 16777216);      // 4352*1024*2  =  8,912,896
  __bf16* wproj = (__bf16*)(ws + 25690112);      // 1024*2048*2  =  4,194,304
  __bf16* h     = (__bf16*)(ws + 29884416);      // 8192*4352*2  = 71,303,168
  __bf16* fused = (__bf16*)(ws + 101187584);     // 8192*2048*2  = 33,554,432
  __bf16* vbuf  = (__bf16*)(ws + 134742016);     // 8192*1024*2  = 16,777,216
  // total 151,519,232 bytes

  ln_kernel<<<MROWS, 256, 0, stream>>>(x, norm_w, xn);
  cast_kernel<<<4352, 256, 0, stream>>>(expand_w, wexp, 4456448 / 4);
  cast_kernel<<<2048, 256, 0, stream>>>(project_w, wproj, 2097152 / 4);
  gemm_bt<0><<<dim3(MROWS / 128, NEXP / 128), 256, 0, stream>>>(xn, wexp, (void*)h, nullptr, NEXP, DDIM);
  geglu_kernel<<<MROWS, 256, 0, stream>>>(h, fused, vbuf);
  attn_kernel<<<MROWS, 256, 0, stream>>>(h, vbuf, fused, pbm);
  gemm_bt<1><<<dim3(MROWS / 128, DDIM / 128), 256, 0, stream>>>(fused, wproj, (void*)out, x, DDIM, EDIM);
}